// Round 2
// baseline (171.254 us; speedup 1.0000x reference)
//
#include <hip/hip_runtime.h>

#define B_ 4
#define C_ 256
#define HH 64
#define WW 64
#define N_ 4096
#define IC_ 128
#define JC_ 8   // j-split factor for correlation

typedef __attribute__((ext_vector_type(8))) short bf16x8;
typedef __attribute__((ext_vector_type(4))) float f32x4;

__device__ __forceinline__ short f2bf(float f) {
    unsigned u = __builtin_bit_cast(unsigned, f);
    unsigned r = (u + 0x7FFFu + ((u >> 16) & 1u)) >> 16;
    return (short)r;
}

__device__ __forceinline__ int refl(int v) {
    return v < 0 ? -v : (v > 63 ? 126 - v : v);
}

// ---------------- K1: projection GEMM (MFMA) -> thetaT/phiT [B][N][IC] bf16 ----
// f32 weights converted inline (k_cvt_w folded in: identical f2bf rounding).
__global__ __launch_bounds__(256) void k_project(
    const float* __restrict__ qf, const float* __restrict__ kf,
    const float* __restrict__ wq, const float* __restrict__ wk,
    const float* __restrict__ bq, const float* __restrict__ bk,
    short* __restrict__ outq, short* __restrict__ outk) {
    int z = blockIdx.z;
    const float* x = z ? kf : qf;
    const float* wf = z ? wk : wq;
    const float* bias = z ? bk : bq;
    short* outT = z ? outk : outq;

    int b = blockIdx.y;
    int n0 = blockIdx.x * 32;
    int t = threadIdx.x;
    int lane = t & 63, wv = t >> 6;
    int l15 = lane & 15, q4 = lane >> 4;
    const float* xb = x + (size_t)b * C_ * N_;

    __shared__ float xs[2][32][36];  // 32 c-rows x 32 n (+pad 4)

    f32x4 acc[2][2];  // [rf][cfi]
#pragma unroll
    for (int rf = 0; rf < 2; rf++)
#pragma unroll
        for (int cfi = 0; cfi < 2; cfi++) acc[rf][cfi] = (f32x4){0.f, 0.f, 0.f, 0.f};

    int sr = t >> 3, sc = t & 7;  // stage: 32 rows x 8 f32x4
    *(f32x4*)(&xs[0][sr][sc * 4]) = *(const f32x4*)(xb + (size_t)sr * N_ + n0 + sc * 4);

    for (int ks = 0; ks < 8; ks++) {
        __syncthreads();
        int buf = ks & 1;
        if (ks < 7) {
            int cb = (ks + 1) * 32;
            *(f32x4*)(&xs[buf ^ 1][sr][sc * 4]) =
                *(const f32x4*)(xb + (size_t)(cb + sr) * N_ + n0 + sc * 4);
        }
        int cbase = ks * 32 + q4 * 8;
        bf16x8 a[2];
#pragma unroll
        for (int rf = 0; rf < 2; rf++)
#pragma unroll
            for (int j = 0; j < 8; j++) a[rf][j] = f2bf(xs[buf][q4 * 8 + j][rf * 16 + l15]);
#pragma unroll
        for (int cfi = 0; cfi < 2; cfi++) {
            int cf = wv * 2 + cfi;
            const float* wrow = wf + (size_t)(cf * 16 + l15) * C_ + cbase;
            f32x4 w0 = *(const f32x4*)(wrow);
            f32x4 w1 = *(const f32x4*)(wrow + 4);
            bf16x8 bfr;
#pragma unroll
            for (int j = 0; j < 4; j++) {
                bfr[j] = f2bf(w0[j]);
                bfr[j + 4] = f2bf(w1[j]);
            }
#pragma unroll
            for (int rf = 0; rf < 2; rf++)
                acc[rf][cfi] = __builtin_amdgcn_mfma_f32_16x16x32_bf16(a[rf], bfr, acc[rf][cfi], 0, 0, 0);
        }
    }
    // Epilogue: D row = q4*4 + r (n within 16), col = l15 (ic within 16)
#pragma unroll
    for (int cfi = 0; cfi < 2; cfi++) {
        int ic = (wv * 2 + cfi) * 16 + l15;
        float bv = bias[ic];
#pragma unroll
        for (int rf = 0; rf < 2; rf++) {
#pragma unroll
            for (int r = 0; r < 4; r++) {
                int n = n0 + rf * 16 + q4 * 4 + r;
                outT[((size_t)b * N_ + n) * IC_ + ic] = f2bf(acc[rf][cfi][r] + bv);
            }
        }
    }
}

// ---------------- K2: correlation + partial row-max (MFMA) ----------------
// 64 i-rows per wave (256 i/block): 16 ds_read_b128 now feed 64 MFMAs per tile
// (FLOP/LDS-byte doubled to 64). Grid 512 blocks = 2/CU; LDS 34.8 KB dbuf.
__global__ __launch_bounds__(256, 2) void k_corr(const short* __restrict__ thetaT,
                                                 const short* __restrict__ phiT,
                                                 float* __restrict__ simp) {
    __shared__ short ph[2][64][136];  // double-buffered 64 j x 128 ic (+8 pad)

    int b = blockIdx.z, jc = blockIdx.y;
    int i0 = blockIdx.x * 256;
    int t = threadIdx.x;
    int lane = t & 63, w = t >> 6;
    int l15 = lane & 15, q4 = lane >> 4;

    const short* thb = thetaT + ((size_t)b * N_ + i0 + w * 64) * IC_;
    const short* phb = phiT + ((size_t)b * N_ + jc * (N_ / JC_)) * IC_;

    bf16x8 afr[4][4];  // 64 i-rows x 128 ic held in regs (64 VGPR)
#pragma unroll
    for (int rf = 0; rf < 4; rf++)
#pragma unroll
        for (int ks = 0; ks < 4; ks++)
            afr[rf][ks] = *(const bf16x8*)(thb + (size_t)(rf * 16 + l15) * IC_ + ks * 32 + q4 * 8);

    int sr = t >> 4, sc8 = t & 15;
#pragma unroll
    for (int k = 0; k < 4; k++)
        *(bf16x8*)(&ph[0][sr + k * 16][sc8 * 8]) =
            *(const bf16x8*)(phb + (size_t)(sr + k * 16) * IC_ + sc8 * 8);

    f32x4 rmax[4];
#pragma unroll
    for (int rf = 0; rf < 4; rf++) rmax[rf] = (f32x4){-3.0e38f, -3.0e38f, -3.0e38f, -3.0e38f};

    const int NT = (N_ / JC_) / 64;  // 8 tiles
    for (int it = 0; it < NT; it++) {
        int buf = it & 1;
        __syncthreads();
        if (it < NT - 1) {
            int j0 = (it + 1) * 64;
#pragma unroll
            for (int k = 0; k < 4; k++)
                *(bf16x8*)(&ph[buf ^ 1][sr + k * 16][sc8 * 8]) =
                    *(const bf16x8*)(phb + (size_t)(j0 + sr + k * 16) * IC_ + sc8 * 8);
        }
#pragma unroll
        for (int jf = 0; jf < 4; jf++) {
            bf16x8 bfr[4];
#pragma unroll
            for (int ks = 0; ks < 4; ks++)
                bfr[ks] = *(const bf16x8*)(&ph[buf][jf * 16 + l15][ks * 32 + q4 * 8]);
#pragma unroll
            for (int rf = 0; rf < 4; rf++) {
                f32x4 a2 = (f32x4){0.f, 0.f, 0.f, 0.f};
#pragma unroll
                for (int ks = 0; ks < 4; ks++)
                    a2 = __builtin_amdgcn_mfma_f32_16x16x32_bf16(afr[rf][ks], bfr[ks], a2, 0, 0, 0);
#pragma unroll
                for (int r = 0; r < 4; r++) rmax[rf][r] = fmaxf(rmax[rf][r], a2[r]);
            }
        }
    }

#pragma unroll
    for (int rf = 0; rf < 4; rf++) {
#pragma unroll
        for (int r = 0; r < 4; r++) {
            float v = rmax[rf][r];
            v = fmaxf(v, __shfl_xor(v, 1));
            v = fmaxf(v, __shfl_xor(v, 2));
            v = fmaxf(v, __shfl_xor(v, 4));
            v = fmaxf(v, __shfl_xor(v, 8));
            rmax[rf][r] = v;
        }
    }
    if (l15 == 0) {
        float* sp = simp + ((size_t)(b * JC_ + jc)) * N_ + i0 + w * 64;
#pragma unroll
        for (int rf = 0; rf < 4; rf++)
#pragma unroll
            for (int r = 0; r < 4; r++) sp[rf * 16 + q4 * 4 + r] = rmax[rf][r];
    }
}

// ---------------- K3: fused conv_in(1->32) + relu conv_r1(32->32) ----------
// Stages 5 max-reduced sim rows, computes the 3-row h_in tile in LDS
// (double-reflection slot math), writes center h_in row (blockIdx.y==0 only),
// then the standard 32->32 conv with oc-split x2.
__global__ __launch_bounds__(256) void k_r1_fused(
    const float* __restrict__ simp,
    const float* __restrict__ win, const float* __restrict__ bin,
    const float* __restrict__ w, const float* __restrict__ bias,
    float* __restrict__ rout, float* __restrict__ hout) {
    int y = blockIdx.x, b = blockIdx.z;
    int oc0 = blockIdx.y * 16;
    int t = threadIdx.x;
    __shared__ float srow[5][66];           // sim rows refl(y-2+d), col-haloed
    __shared__ float tile[32][3][68];       // h_in rows refl(y-1+r), +1 col shift
    __shared__ float wlds[32 * 16 * 12];    // r1 weights [ic][ocl][12]
    __shared__ float wi[288];               // conv_in weights
    __shared__ float bi[32];

    for (int k = t; k < 288; k += 256) wi[k] = win[k];   // FIX: 288 > blockDim
    if (t < 32) bi[t] = bin[t];

    const float* sb = simp + (size_t)b * JC_ * N_;
    for (int idx = t; idx < 330; idx += 256) {
        int d = idx / 66, cc = idx - d * 66;
        int row = refl(y - 2 + d);
        int col = refl(cc - 1);
        float v = -3.0e38f;
#pragma unroll
        for (int jc = 0; jc < JC_; jc++) v = fmaxf(v, sb[jc * N_ + row * 64 + col]);
        srow[d][cc] = v;
    }

#pragma unroll
    for (int k = 0; k < 18; k++) {
        int id = t + k * 256;              // 0..4607
        int ocl = id / 288;
        int rem = id - ocl * 288;
        int ic = rem / 9;
        int tap = rem - ic * 9;
        wlds[(ic * 16 + ocl) * 12 + tap] = w[(size_t)(oc0 + ocl) * 288 + rem];
    }
    __syncthreads();

    // compute h_in tile: rows gy = refl(y-1+r); srow slot = refl(src) - y + 2
    {
        int ic = t >> 3, xg = t & 7;
        float bv = bi[ic];
        float wr[9];
#pragma unroll
        for (int k2 = 0; k2 < 9; k2++) wr[k2] = wi[ic * 9 + k2];
#pragma unroll
        for (int r = 0; r < 3; r++) {
            int gy = refl(y - 1 + r);
            int s0 = refl(gy - 1) - y + 2;
            int s1 = gy - y + 2;
            int s2 = refl(gy + 1) - y + 2;
#pragma unroll
            for (int k2 = 0; k2 < 9; k2++) {
                int xs = k2 * 8 + xg;
                if (xs < 66) {
                    int cp = refl(xs - 1);  // h_in output col (col-reflected)
                    float a = bv;
                    a += wr[0] * srow[s0][cp];
                    a += wr[1] * srow[s0][cp + 1];
                    a += wr[2] * srow[s0][cp + 2];
                    a += wr[3] * srow[s1][cp];
                    a += wr[4] * srow[s1][cp + 1];
                    a += wr[5] * srow[s1][cp + 2];
                    a += wr[6] * srow[s2][cp];
                    a += wr[7] * srow[s2][cp + 1];
                    a += wr[8] * srow[s2][cp + 2];
                    tile[ic][r][xs] = a;
                }
            }
        }
    }
    __syncthreads();

    // persist center h_in row (r=1 -> gy == y always) for the residual add
    if (blockIdx.y == 0) {
        for (int idx = t; idx < 2048; idx += 256) {
            int ic = idx >> 6, x = idx & 63;
            hout[(((size_t)b * 32 + ic) * 64 + y) * 64 + x] = tile[ic][1][x + 1];
        }
    }

    int ocl = t >> 4, x4 = (t & 15) * 4;
    float bv = bias[oc0 + ocl];
    float acc[4];
#pragma unroll
    for (int xi = 0; xi < 4; xi++) acc[xi] = bv;

#pragma unroll 2
    for (int ic = 0; ic < 32; ic++) {
        const float* wr = &wlds[(ic * 16 + ocl) * 12];
        f32x4 W0 = *(const f32x4*)(wr);
        f32x4 W1 = *(const f32x4*)(wr + 4);
        f32x4 W2 = *(const f32x4*)(wr + 8);
        float w0 = W0[0], w1 = W0[1], w2 = W0[2], w3 = W0[3];
        float w4 = W1[0], w5 = W1[1], w6 = W1[2], w7 = W1[3];
        float w8 = W2[0];
        float xr[3][8];
#pragma unroll
        for (int r = 0; r < 3; r++) {
            const float* rowp = &tile[ic][r][x4];
            f32x4 A = *(const f32x4*)(rowp);
            f32x4 Bv = *(const f32x4*)(rowp + 4);
            xr[r][0] = A[0]; xr[r][1] = A[1]; xr[r][2] = A[2]; xr[r][3] = A[3];
            xr[r][4] = Bv[0]; xr[r][5] = Bv[1]; xr[r][6] = Bv[2]; xr[r][7] = Bv[3];
        }
#pragma unroll
        for (int xi = 0; xi < 4; xi++) {
            acc[xi] += w0 * xr[0][xi] + w1 * xr[0][xi + 1] + w2 * xr[0][xi + 2] +
                       w3 * xr[1][xi] + w4 * xr[1][xi + 1] + w5 * xr[1][xi + 2] +
                       w6 * xr[2][xi] + w7 * xr[2][xi + 1] + w8 * xr[2][xi + 2];
        }
    }
    size_t off = (((size_t)b * 32 + oc0 + ocl) * 64 + y) * 64 + x4;
#pragma unroll
    for (int xi = 0; xi < 4; xi++) rout[off + xi] = fmaxf(acc[xi], 0.f);
}

// ---------------- K4: conv 32 -> 32 (+add), reflect pad, oc-split x2 ----
template <bool RELU, bool ADD>
__global__ __launch_bounds__(256) void k_conv_r(const float* __restrict__ in,
                                                const float* __restrict__ w,
                                                const float* __restrict__ bias,
                                                float* __restrict__ out,
                                                const float* __restrict__ add) {
    int y = blockIdx.x, b = blockIdx.z;
    int oc0 = blockIdx.y * 16;
    int t = threadIdx.x;
    __shared__ float tile[32][3][68];
    __shared__ float wlds[32 * 16 * 12];

#pragma unroll
    for (int k = 0; k < 18; k++) {
        int id = t + k * 256;
        int ocl = id / 288;
        int rem = id - ocl * 288;
        int ic = rem / 9;
        int tap = rem - ic * 9;
        wlds[(ic * 16 + ocl) * 12 + tap] = w[(size_t)(oc0 + ocl) * 288 + rem];
    }

#pragma unroll
    for (int r = 0; r < 3; r++) {
        int gy = refl(y - 1 + r);
#pragma unroll
        for (int i = 0; i < 2; i++) {
            int idx = t + i * 256;
            int ic = idx >> 4, c4 = idx & 15;
            f32x4 v = *(const f32x4*)(in + (((size_t)b * 32 + ic) * 64 + gy) * 64 + c4 * 4);
#pragma unroll
            for (int s = 0; s < 4; s++) tile[ic][r][c4 * 4 + s + 1] = v[s];
        }
    }
    if (t < 96) {
        int ic = t / 3, r = t - ic * 3;
        int gy = refl(y - 1 + r);
        const float* row = in + (((size_t)b * 32 + ic) * 64 + gy) * 64;
        tile[ic][r][0] = row[1];
        tile[ic][r][65] = row[62];
    }
    __syncthreads();

    int ocl = t >> 4, x4 = (t & 15) * 4;
    float bv = bias[oc0 + ocl];
    float acc[4];
#pragma unroll
    for (int xi = 0; xi < 4; xi++) acc[xi] = bv;

#pragma unroll 2
    for (int ic = 0; ic < 32; ic++) {
        const float* wr = &wlds[(ic * 16 + ocl) * 12];
        f32x4 W0 = *(const f32x4*)(wr);
        f32x4 W1 = *(const f32x4*)(wr + 4);
        f32x4 W2 = *(const f32x4*)(wr + 8);
        float w0 = W0[0], w1 = W0[1], w2 = W0[2], w3 = W0[3];
        float w4 = W1[0], w5 = W1[1], w6 = W1[2], w7 = W1[3];
        float w8 = W2[0];
        float xr[3][8];
#pragma unroll
        for (int r = 0; r < 3; r++) {
            const float* rowp = &tile[ic][r][x4];
            f32x4 A = *(const f32x4*)(rowp);
            f32x4 Bv = *(const f32x4*)(rowp + 4);
            xr[r][0] = A[0]; xr[r][1] = A[1]; xr[r][2] = A[2]; xr[r][3] = A[3];
            xr[r][4] = Bv[0]; xr[r][5] = Bv[1]; xr[r][6] = Bv[2]; xr[r][7] = Bv[3];
        }
#pragma unroll
        for (int xi = 0; xi < 4; xi++) {
            acc[xi] += w0 * xr[0][xi] + w1 * xr[0][xi + 1] + w2 * xr[0][xi + 2] +
                       w3 * xr[1][xi] + w4 * xr[1][xi + 1] + w5 * xr[1][xi + 2] +
                       w6 * xr[2][xi] + w7 * xr[2][xi + 1] + w8 * xr[2][xi + 2];
        }
    }
    size_t off = (((size_t)b * 32 + oc0 + ocl) * 64 + y) * 64 + x4;
#pragma unroll
    for (int xi = 0; xi < 4; xi++) {
        float v = acc[xi];
        if (RELU) v = fmaxf(v, 0.f);
        if (ADD) v += add[off + xi];
        out[off + xi] = v;
    }
}

// ---------------- K5: conv_out 32 -> 1 (ic split 4-way + LDS reduce) ----
__global__ __launch_bounds__(256) void k_conv_out(const float* __restrict__ hb,
                                                  const float* __restrict__ w,
                                                  const float* __restrict__ bias,
                                                  float* __restrict__ outp) {
    int y = blockIdx.x, b = blockIdx.y;
    int t = threadIdx.x;
    int x = t & 63, g = t >> 6;
    __shared__ float red[4][64];
    __shared__ float wl[288];
    for (int k = t; k < 288; k += 256) wl[k] = w[k];
    __syncthreads();
    float acc = 0.f;
#pragma unroll
    for (int i = 0; i < 8; i++) {
        int ic = g * 8 + i;
        const float* wp = wl + ic * 9;
#pragma unroll
        for (int ky = 0; ky < 3; ky++) {
            int gy = refl(y + ky - 1);
            const float* row = hb + (((size_t)b * 32 + ic) * 64 + gy) * 64;
#pragma unroll
            for (int kx = 0; kx < 3; kx++) {
                int gx = refl(x + kx - 1);
                acc += wp[ky * 3 + kx] * row[gx];
            }
        }
    }
    red[g][x] = acc;
    __syncthreads();
    if (t < 64) {
        outp[((size_t)b * 64 + y) * 64 + x] =
            bias[0] + red[0][t] + red[1][t] + red[2][t] + red[3][t];
    }
}

extern "C" void kernel_launch(void* const* d_in, const int* in_sizes, int n_in,
                              void* d_out, int out_size, void* d_ws, size_t ws_size,
                              hipStream_t stream) {
    const float* q = (const float*)d_in[0];
    const float* kf = (const float*)d_in[1];
    const float* w_theta = (const float*)d_in[2];
    const float* b_theta = (const float*)d_in[3];
    const float* w_phi = (const float*)d_in[4];
    const float* b_phi = (const float*)d_in[5];
    const float* w_in = (const float*)d_in[6];
    const float* b_in = (const float*)d_in[7];
    const float* w_r1 = (const float*)d_in[8];
    const float* b_r1 = (const float*)d_in[9];
    const float* w_r2 = (const float*)d_in[10];
    const float* b_r2 = (const float*)d_in[11];
    const float* w_out = (const float*)d_in[12];
    const float* b_out = (const float*)d_in[13];
    float* out = (float*)d_out;

    char* ws = (char*)d_ws;
    short* thetaT = (short*)(ws);                 // 4 MiB (reused as h/r after k_corr)
    short* phiT = (short*)(ws + 4194304);         // 4 MiB
    float* simp = (float*)(ws + 8519680);         // 512 KiB [B][JC][N]
    float* h = (float*)(ws);                      // 2 MiB (over thetaT, dead by then)
    float* r = (float*)(ws + 2097152);            // 2 MiB

    k_project<<<dim3(128, 4, 2), 256, 0, stream>>>(q, kf, w_theta, w_phi, b_theta, b_phi,
                                                   thetaT, phiT);
    k_corr<<<dim3(16, JC_, 4), 256, 0, stream>>>(thetaT, phiT, simp);
    k_r1_fused<<<dim3(64, 2, 4), 256, 0, stream>>>(simp, w_in, b_in, w_r1, b_r1, r, h);
    k_conv_r<false, true><<<dim3(64, 2, 4), 256, 0, stream>>>(r, w_r2, b_r2, h, h);
    k_conv_out<<<dim3(64, 4), 256, 0, stream>>>(h, w_out, b_out, out);
}